// Round 5
// baseline (409.088 us; speedup 1.0000x reference)
//
#include <hip/hip_runtime.h>
#include <stdint.h>

// Bilinear: out[b,i,j,k] = sum_{p,q} x1[b,i,p] W[k,p,q] x2[b,j,q] + bias[k]
// B=8, L=256, P=Q=512, K=64.
//
//  - pre-convert W/x1/x2 -> bf16 into ws head (36 MiB)
//  - Stage A: S[(b,j),(k,p)] = sum_q X2b[(b,j),q] * Wb[(k,p),q]   (S bf16)
//  - Stage B: out[b,i,(j,k)] = sum_p X1b[i,p] * S_b[(j,k),p] + bias[k]
//
// R5: same proven schedule as R4 (counted vmcnt FIFO, one barrier/K-tile,
// XOR swizzle, XCD m-minor swizzle, j-inner epilogue) with ONE change:
// BK 64->32 so double-buffered LDS drops 96->48 KiB -> 2 BLOCKS/CU
// (__launch_bounds__(512,4), VGPR<=128). R1-R4 all ran 1 block/CU
// (Occupancy ~20%): per-CU wall was 28.5K cyc/block vs ~6K cyc of
// identifiable work -- the gap is non-overlapped prologue/epilogue/barrier
// lockstep, which a second resident block hides (R0's 4-block/CU baseline
// was fast for exactly this reason despite 8.4M bank conflicts).
// Reg-staged (NO global_load_lds - diverged under graph replay previously).

typedef __bf16 bf16x8 __attribute__((ext_vector_type(8)));
typedef float  f32x4  __attribute__((ext_vector_type(4)));

#define KDIM 512
#define BM 256
#define BN 128
#define BK 32
#define NKT (KDIM / BK)         // 16 K-tiles
#define ABYTES 16384            // 256 rows x 64 B
#define BUFB   24576            // bytes per double-buffer half (A 16K + B 8K)

__global__ __launch_bounds__(256) void f32_to_bf16_kernel(
    const float* __restrict__ in, __bf16* __restrict__ out, long n8)
{
    for (long i = blockIdx.x * 256L + threadIdx.x; i < n8; i += gridDim.x * 256L) {
        f32x4 a = *(const f32x4*)(in + i * 8);
        f32x4 b = *(const f32x4*)(in + i * 8 + 4);
        bf16x8 o;
        o[0]=(__bf16)a[0]; o[1]=(__bf16)a[1]; o[2]=(__bf16)a[2]; o[3]=(__bf16)a[3];
        o[4]=(__bf16)b[0]; o[5]=(__bf16)b[1]; o[6]=(__bf16)b[2]; o[7]=(__bf16)b[3];
        *(bf16x8*)(out + i * 8) = o;
    }
}

// ---- schedule primitives ----
#define VMW(N) do { \
    asm volatile("s_waitcnt vmcnt(" #N ")" ::: "memory"); \
    __builtin_amdgcn_sched_barrier(0); } while (0)
#define LGKM0() do { \
    asm volatile("s_waitcnt lgkmcnt(0)" ::: "memory"); \
    __builtin_amdgcn_sched_barrier(0); } while (0)
#define SB() __builtin_amdgcn_sched_barrier(0)

// ---- staging: 3 bf16x8 loads / thread / K-tile ----
// thread covers A rows {tid>>2, tid>>2+128} and B row {tid>>2}, 16-B chunk tid&3.
#define LG(kt) do { \
    e0 = *(const bf16x8*)(gA + (kt) * BK); \
    e1 = *(const bf16x8*)(gA + 128L * KDIM + (kt) * BK); \
    e2 = *(const bf16x8*)(gB + (kt) * BK); } while (0)
#define WG(bi) do { char* w_ = lds + (bi) * BUFB; \
    *(bf16x8*)(w_ + sbw)          = e0; \
    *(bf16x8*)(w_ + 8192 + sbw)   = e1; \
    *(bf16x8*)(w_ + ABYTES + sbw) = e2; } while (0)

// ---- fragment reads (swizzle: 16-B chunk ^= row&3; ko uniform per lane) ----
#define RDB(bi) do { const char* b_ = lds + (bi) * BUFB + ABYTES; \
    _Pragma("unroll") for (int j_ = 0; j_ < 4; ++j_) \
        bfr[j_] = *(const bf16x8*)(b_ + (wn * 64 + j_ * 16 + lcol) * 64 + ko); \
    } while (0)
#define RDA(bi) do { const char* a_ = lds + (bi) * BUFB; \
    _Pragma("unroll") for (int i_ = 0; i_ < 4; ++i_) \
        af[i_] = *(const bf16x8*)(a_ + (wm * 64 + i_ * 16 + lcol) * 64 + ko); \
    } while (0)
#define MF() do { \
    _Pragma("unroll") for (int i_ = 0; i_ < 4; ++i_) \
    _Pragma("unroll") for (int j_ = 0; j_ < 4; ++j_) \
        acc[i_][j_] = __builtin_amdgcn_mfma_f32_16x16x32_bf16( \
            af[i_], bfr[j_], acc[i_][j_], 0, 0, 0); } while (0)

template <typename OutT>
__global__ __launch_bounds__(512, 4) void gemm_nt_r5(
    const __bf16* __restrict__ A,    // [M x 512] row-major
    const __bf16* __restrict__ B,    // [N x 512] row-major  (C = A * B^T)
    OutT* __restrict__ C,            // [M x ldc] row-major
    const float* __restrict__ bias,  // nullptr, or [64]: adds bias[col & 63]
    int ldc, int mtiles,             // m-tiles per z-slice (m-minor tile order)
    long sA, long sB, long sC)       // per-z strides (elements)
{
    __shared__ __align__(16) char lds[2 * BUFB];   // 48 KiB -> 2 blocks/CU

    const int tid  = threadIdx.x;
    const int lane = tid & 63;
    const int wave = tid >> 6;        // 0..7
    const int wm   = wave & 3;        // 4 M-waves (64 rows each)
    const int wn   = wave >> 2;       // 2 N-waves (64 cols each)
    const int lcol = lane & 15;
    const int krow = (lane >> 4) & 3;
    // read byte-offset within a 64-B row: chunk krow, swizzled by row&3 (= lcol&3)
    const int ko   = (krow * 16) ^ ((lcol & 3) << 4);

    // Bijective XCD swizzle over the flattened grid (m204 formula).
    long flat = (long)blockIdx.z * gridDim.x + blockIdx.x;
    long nwg  = (long)gridDim.x * gridDim.z;
    long q = nwg >> 3, r8 = nwg & 7;
    long xcd = flat & 7, lo = flat >> 3;
    long sz = (xcd < r8 ? xcd * (q + 1) : r8 * (q + 1) + (xcd - r8) * q) + lo;
    const int z   = (int)(sz / (long)gridDim.x);
    const int rem = (int)(sz % (long)gridDim.x);
    const int n0 = (rem / mtiles) * BN;   // m-minor: same n-tile (W panel)
    const int m0 = (rem % mtiles) * BM;   // stays on one XCD's L2

    A += (long)z * sA + (long)m0 * KDIM;
    B += (long)z * sB + (long)n0 * KDIM;
    C += (long)z * sC;

    // Staging indices: row = tid>>2 (0..127), 16-B chunk c = tid&3.
    // LDS write offset swizzled the same way the reads expect (chunk ^= row&3).
    const int r  = tid >> 2;
    const int c4 = tid & 3;
    const int sbw = r * 64 + ((c4 * 16) ^ ((r & 3) << 4));
    const __bf16* gA = A + (long)r * KDIM + c4 * 8;
    const __bf16* gB = B + (long)r * KDIM + c4 * 8;

    bf16x8 e0, e1, e2;                // in-flight staging regs (1 tile = 3 loads)
    f32x4 acc[4][4] = {};

    // ---- prologue: tiles 0,1 issued; tile0 -> buf0 ----
    LG(0);                            // 3 outstanding
    {   bf16x8 t0 = e0, t1 = e1, t2 = e2;  // keep tile0 regs while issuing t1
        LG(1);                        // 6 outstanding (t1 in e*, t0 in t*)
        VMW(3);                       // t0 arrived
        char* w_ = lds;
        *(bf16x8*)(w_ + sbw)          = t0;
        *(bf16x8*)(w_ + 8192 + sbw)   = t1;
        *(bf16x8*)(w_ + ABYTES + sbw) = t2;
    }
    LGKM0();
    __builtin_amdgcn_s_barrier(); SB();

    // ---- main loop: tiles 0..13 ----
#pragma unroll
    for (int t = 0; t < NKT - 2; ++t) {
        const int cur = t & 1, nxt = cur ^ 1;
        bf16x8 bfr[4], af[4];
        RDB(cur); RDA(cur);
        {   bf16x8 p0 = e0, p1 = e1, p2 = e2;   // t+1's loads (in flight)
            LG(t + 2);                           // issue t+2 (6 outstanding)
            VMW(3);                              // t+1 arrived (in p*)
            char* w_ = lds + nxt * BUFB;
            *(bf16x8*)(w_ + sbw)          = p0;
            *(bf16x8*)(w_ + 8192 + sbw)   = p1;
            *(bf16x8*)(w_ + ABYTES + sbw) = p2;
        }
        SB();
        __builtin_amdgcn_s_setprio(1); MF(); __builtin_amdgcn_s_setprio(0);
        LGKM0();
        __builtin_amdgcn_s_barrier(); SB();
    }
    {   // tile 14 (buf0): write tile15 -> buf1, nothing more to issue
        bf16x8 bfr[4], af[4];
        RDB(0); RDA(0);
        VMW(0); WG(1); SB();
        __builtin_amdgcn_s_setprio(1); MF(); __builtin_amdgcn_s_setprio(0);
        LGKM0();
        __builtin_amdgcn_s_barrier(); SB();
    }
    {   // tile 15 (buf1): reads + MFMA only
        bf16x8 bfr[4], af[4];
        RDB(1); RDA(1); MF();
    }

    // Epilogue. C/D layout (16x16): col = lane&15, row = (lane>>4)*4 + reg.
    // j innermost: each (i,rr) completes 64 consecutive cols = full lines.
    float badd[4];
#pragma unroll
    for (int j = 0; j < 4; ++j)
        badd[j] = bias ? bias[j * 16 + lcol] : 0.f;
#pragma unroll
    for (int i = 0; i < 4; ++i) {
#pragma unroll
        for (int rr = 0; rr < 4; ++rr) {
            const int row = m0 + wm * 64 + i * 16 + krow * 4 + rr;
            OutT* cp = C + (long)row * ldc + n0 + wn * 64 + lcol;
#pragma unroll
            for (int j = 0; j < 4; ++j)
                cp[j * 16] = (OutT)(acc[i][j][rr] + badd[j]);
        }
    }
}

extern "C" void kernel_launch(void* const* d_in, const int* in_sizes, int n_in,
                              void* d_out, int out_size, void* d_ws, size_t ws_size,
                              hipStream_t stream)
{
    (void)in_sizes; (void)n_in; (void)out_size;
    const float* x1f = (const float*)d_in[0];  // [8,256,512]
    const float* x2f = (const float*)d_in[1];  // [8,256,512]
    const float* Wf  = (const float*)d_in[2];  // [64,512,512]
    const float* bs  = (const float*)d_in[3];  // [64]
    float* out = (float*)d_out;                // [8,256,256,64]

    const long N_W = 64L * 512 * 512;
    const long N_X = 8L * 256 * 512;
    __bf16* Wb  = (__bf16*)d_ws;
    __bf16* x1b = Wb + N_W;
    __bf16* x2b = x1b + N_X;
    __bf16* S   = x2b + N_X;
    const size_t head_bytes = (size_t)(N_W + 2 * N_X) * sizeof(__bf16); // 36 MiB

    f32_to_bf16_kernel<<<2048, 256, 0, stream>>>(Wf,  Wb,  N_W / 8);
    f32_to_bf16_kernel<<<512,  256, 0, stream>>>(x1f, x1b, N_X / 8);
    f32_to_bf16_kernel<<<512,  256, 0, stream>>>(x2f, x2b, N_X / 8);

    const long ROWS_TOTAL = 2048;              // S rows = (b,j)
    const long ROW_ELEMS  = 32768;             // (k,p) per S row

    long rows_chunk = (ws_size > head_bytes)
        ? (long)((ws_size - head_bytes) / (ROW_ELEMS * sizeof(__bf16))) : 0;
    rows_chunk &= ~255L;
    if (rows_chunk < 256) rows_chunk = 256;
    if (rows_chunk > ROWS_TOTAL) rows_chunk = ROWS_TOTAL;

    for (long r0 = 0; r0 < ROWS_TOTAL; r0 += rows_chunk) {
        long rows = ROWS_TOTAL - r0;
        if (rows > rows_chunk) rows = rows_chunk;
        long nbc = rows >> 8;                  // whole b's this chunk
        int  mt  = (int)(rows >> 8);           // 256-row m-tiles

        // Stage A: S = X2b @ Wb^T.  M = rows, N = 32768, K = 512.
        dim3 gA((unsigned)((32768 / BN) * mt), 1, 1);
        gemm_nt_r5<__bf16><<<gA, 512, 0, stream>>>(
            x2b + r0 * KDIM, Wb, S, nullptr, 32768, mt, 0, 0, 0);

        // Stage B: z-batched over this chunk's b's -> fp32 out (+bias).
        dim3 gB2(16384 / BN, 1, (unsigned)nbc);
        gemm_nt_r5<float><<<gB2, 512, 0, stream>>>(
            x1b + r0 * KDIM,                   // X1_b rows
            S,                                 // S_b as [16384 x 512]
            out + r0 * 16384,                  // out_b as [256 x 16384]
            bs, 16384, 1,
            256L * KDIM, 256L * ROW_ELEMS, 256L * 16384);
    }
}

// Round 7
// 322.977 us; speedup vs baseline: 1.2666x; 1.2666x over previous
//
#include <hip/hip_runtime.h>
#include <stdint.h>

// Bilinear: out[b,i,j,k] = sum_{p,q} x1[b,i,p] W[k,p,q] x2[b,j,q] + bias[k]
// B=8, L=256, P=Q=512, K=64.
//
//  - pre-convert W/x1/x2 -> bf16 into ws head (36 MiB)
//  - Stage A: S[(b,j),(k,p)] = sum_q X2b[(b,j),q] * Wb[(k,p),q]   (S bf16)
//  - Stage B: out[b,i,(j,k)] = sum_p X1b[i,p] * S_b[(j,k),p] + bias[k]
//
// R7 = R6 resubmitted verbatim after a second infra-side container failure
// (same signature as R3 -> identical R4 resubmission passed; kernel
// re-audited: uniform barriers, self-only waitcnts, read/write hazards
// barrier-protected, 48 KiB LDS / ~112 VGPR in budget, no OOB).
//
// R6 = R4's proven memory behavior + R5's proven residency:
//   tile 256x128, BK=64 (128-B LDS rows: swizzle proven conflict-free in R4,
//   fetch stays 128-B-line aligned -- R5's BK=32 broke both), 8 waves 4Mx2N,
//   SINGLE-buffered LDS 48 KiB -> 2 blocks/CU (R1-R4 ran 1 block/CU,
//   occupancy 20%, barrier/prologue stalls had nothing to overlap; R5 proved
//   occupancy rises to ~41% with 2 blocks). 2 raw barriers per K-tile
//   (lgkmcnt-only drain; vmcnt NEVER force-drained -- next tile's 6 global
//   loads are issued before compute and consumed at the ds_write where the
//   compiler inserts the counted vmcnt wait). Reg-staged (NO global_load_lds
//   - diverged under graph replay in a prior session). T1 bijective XCD
//   swizzle m-minor (FETCH 164->53 MB proven), j-inner epilogue (WRITE
//   321->131 MB proven). Frag reads per-kk/per-i to keep VGPR ~112 (<128,
//   no spill at __launch_bounds__(512,4)).

typedef __bf16 bf16x8 __attribute__((ext_vector_type(8)));
typedef float  f32x4  __attribute__((ext_vector_type(4)));

#define KDIM 512
#define BM 256
#define BN 128
#define BK 64
#define NKT (KDIM / BK)         // 8 K-tiles
#define ABYTES 32768            // A: 256 rows x 128 B
#define LDSB   49152            // + B: 128 rows x 128 B (single buffer)

__global__ __launch_bounds__(256) void f32_to_bf16_kernel(
    const float* __restrict__ in, __bf16* __restrict__ out, long n8)
{
    for (long i = blockIdx.x * 256L + threadIdx.x; i < n8; i += gridDim.x * 256L) {
        f32x4 a = *(const f32x4*)(in + i * 8);
        f32x4 b = *(const f32x4*)(in + i * 8 + 4);
        bf16x8 o;
        o[0]=(__bf16)a[0]; o[1]=(__bf16)a[1]; o[2]=(__bf16)a[2]; o[3]=(__bf16)a[3];
        o[4]=(__bf16)b[0]; o[5]=(__bf16)b[1]; o[6]=(__bf16)b[2]; o[7]=(__bf16)b[3];
        *(bf16x8*)(out + i * 8) = o;
    }
}

// ---- schedule primitives ----
#define LGKM0() do { \
    asm volatile("s_waitcnt lgkmcnt(0)" ::: "memory"); \
    __builtin_amdgcn_sched_barrier(0); } while (0)
#define SB() __builtin_amdgcn_sched_barrier(0)
#define BAR() do { __builtin_amdgcn_s_barrier(); SB(); } while (0)

// ---- staging: 6 bf16x8 loads / thread / K-tile ----
// thread covers A rows r+{0,64,128,192}, B rows r+{0,64}, 16-B chunk c8.
#define LG(kt) do { \
    e0 = *(const bf16x8*)(gA + (kt) * BK); \
    e1 = *(const bf16x8*)(gA + 64L * KDIM + (kt) * BK); \
    e2 = *(const bf16x8*)(gA + 128L * KDIM + (kt) * BK); \
    e3 = *(const bf16x8*)(gA + 192L * KDIM + (kt) * BK); \
    f0 = *(const bf16x8*)(gB + (kt) * BK); \
    f1 = *(const bf16x8*)(gB + 64L * KDIM + (kt) * BK); } while (0)
// WG: compiler inserts the needed s_waitcnt vmcnt(N) on first reg use.
#define WG() do { \
    *(bf16x8*)(lds + sbw)                  = e0; \
    *(bf16x8*)(lds + 8192 + sbw)           = e1; \
    *(bf16x8*)(lds + 16384 + sbw)          = e2; \
    *(bf16x8*)(lds + 24576 + sbw)          = e3; \
    *(bf16x8*)(lds + ABYTES + sbw)         = f0; \
    *(bf16x8*)(lds + ABYTES + 8192 + sbw)  = f1; } while (0)

// ---- compute one K-tile from LDS (per-kk, per-i frag reads: ~112 VGPR) ----
#define COMPUTE() do { \
    _Pragma("unroll") for (int kk_ = 0; kk_ < 2; ++kk_) { \
        const int ko_ = (kk_ * 64 + krow * 16) ^ rsw; \
        bf16x8 bfr[4]; \
        _Pragma("unroll") for (int j_ = 0; j_ < 4; ++j_) \
            bfr[j_] = *(const bf16x8*)(lds + ABYTES + (wn * 64 + j_ * 16 + lcol) * 128 + ko_); \
        _Pragma("unroll") for (int i_ = 0; i_ < 4; ++i_) { \
            bf16x8 af = *(const bf16x8*)(lds + (wm * 64 + i_ * 16 + lcol) * 128 + ko_); \
            _Pragma("unroll") for (int j_ = 0; j_ < 4; ++j_) \
                acc[i_][j_] = __builtin_amdgcn_mfma_f32_16x16x32_bf16( \
                    af, bfr[j_], acc[i_][j_], 0, 0, 0); \
        } } } while (0)

template <typename OutT>
__global__ __launch_bounds__(512, 4) void gemm_nt_r6(
    const __bf16* __restrict__ A,    // [M x 512] row-major
    const __bf16* __restrict__ B,    // [N x 512] row-major  (C = A * B^T)
    OutT* __restrict__ C,            // [M x ldc] row-major
    const float* __restrict__ bias,  // nullptr, or [64]: adds bias[col & 63]
    int ldc, int mtiles,             // m-tiles per z-slice (m-minor tile order)
    long sA, long sB, long sC)       // per-z strides (elements)
{
    __shared__ __align__(16) char lds[LDSB];   // 48 KiB -> 2 blocks/CU

    const int tid  = threadIdx.x;
    const int lane = tid & 63;
    const int wave = tid >> 6;        // 0..7
    const int wm   = wave & 3;        // 4 M-waves (64 rows each)
    const int wn   = wave >> 2;       // 2 N-waves (64 cols each)
    const int lcol = lane & 15;
    const int krow = (lane >> 4) & 3;
    const int rsw  = (lcol & 7) << 4; // row&7 == lcol&7 for all frag rows

    // Bijective XCD swizzle over the flattened grid (m204 formula).
    long flat = (long)blockIdx.z * gridDim.x + blockIdx.x;
    long nwg  = (long)gridDim.x * gridDim.z;
    long q = nwg >> 3, r8 = nwg & 7;
    long xcd = flat & 7, lo = flat >> 3;
    long sz = (xcd < r8 ? xcd * (q + 1) : r8 * (q + 1) + (xcd - r8) * q) + lo;
    const int z   = (int)(sz / (long)gridDim.x);
    const int rem = (int)(sz % (long)gridDim.x);
    const int n0 = (rem / mtiles) * BN;   // m-minor: same n-tile (W panel)
    const int m0 = (rem % mtiles) * BM;   // stays on one XCD's L2

    A += (long)z * sA + (long)m0 * KDIM;
    B += (long)z * sB + (long)n0 * KDIM;
    C += (long)z * sC;

    // Staging indices: row = tid>>3 (0..63), 16-B chunk c8 = tid&7.
    // XOR-swizzled LDS byte offset (proven conflict-free at 128-B rows, R4).
    const int r  = tid >> 3;
    const int c8 = tid & 7;
    const int sbw = r * 128 + ((c8 * 16) ^ ((r & 7) << 4));
    const __bf16* gA = A + (long)r * KDIM + c8 * 8;
    const __bf16* gB = B + (long)r * KDIM + c8 * 8;

    bf16x8 e0, e1, e2, e3, f0, f1;    // staging regs (24 VGPR, 1 tile in flight)
    f32x4 acc[4][4] = {};

    // ---- prologue: tile 0 -> LDS ----
    LG(0);
    WG();                             // vmcnt waits auto-inserted
    LGKM0();
    BAR();

    // ---- main loop: tiles 0..6; prefetch t+1 issued before compute ----
#pragma unroll
    for (int t = 0; t < NKT - 1; ++t) {
        LG(t + 1); SB();              // 6 loads in flight across compute
        COMPUTE();                    // tile t from LDS (compiler lgkmcnt)
        LGKM0();                      // my ds_reads drained
        BAR();                        // all waves done reading tile t
        WG();                         // write tile t+1 (vmcnt auto)
        LGKM0();                      // my ds_writes drained
        BAR();                        // tile t+1 visible to all
    }
    COMPUTE();                        // tile 7

    // Epilogue. C/D layout (16x16): col = lane&15, row = (lane>>4)*4 + reg.
    // j innermost: each row's 64-col span completes in consecutive stores.
    float badd[4];
#pragma unroll
    for (int j = 0; j < 4; ++j)
        badd[j] = bias ? bias[j * 16 + lcol] : 0.f;
#pragma unroll
    for (int i = 0; i < 4; ++i) {
#pragma unroll
        for (int rr = 0; rr < 4; ++rr) {
            const int row = m0 + wm * 64 + i * 16 + krow * 4 + rr;
            OutT* cp = C + (long)row * ldc + n0 + wn * 64 + lcol;
#pragma unroll
            for (int j = 0; j < 4; ++j)
                cp[j * 16] = (OutT)(acc[i][j][rr] + badd[j]);
        }
    }
}

extern "C" void kernel_launch(void* const* d_in, const int* in_sizes, int n_in,
                              void* d_out, int out_size, void* d_ws, size_t ws_size,
                              hipStream_t stream)
{
    (void)in_sizes; (void)n_in; (void)out_size;
    const float* x1f = (const float*)d_in[0];  // [8,256,512]
    const float* x2f = (const float*)d_in[1];  // [8,256,512]
    const float* Wf  = (const float*)d_in[2];  // [64,512,512]
    const float* bs  = (const float*)d_in[3];  // [64]
    float* out = (float*)d_out;                // [8,256,256,64]

    const long N_W = 64L * 512 * 512;
    const long N_X = 8L * 256 * 512;
    __bf16* Wb  = (__bf16*)d_ws;
    __bf16* x1b = Wb + N_W;
    __bf16* x2b = x1b + N_X;
    __bf16* S   = x2b + N_X;
    const size_t head_bytes = (size_t)(N_W + 2 * N_X) * sizeof(__bf16); // 36 MiB

    f32_to_bf16_kernel<<<2048, 256, 0, stream>>>(Wf,  Wb,  N_W / 8);
    f32_to_bf16_kernel<<<512,  256, 0, stream>>>(x1f, x1b, N_X / 8);
    f32_to_bf16_kernel<<<512,  256, 0, stream>>>(x2f, x2b, N_X / 8);

    const long ROWS_TOTAL = 2048;              // S rows = (b,j)
    const long ROW_ELEMS  = 32768;             // (k,p) per S row

    long rows_chunk = (ws_size > head_bytes)
        ? (long)((ws_size - head_bytes) / (ROW_ELEMS * sizeof(__bf16))) : 0;
    rows_chunk &= ~255L;
    if (rows_chunk < 256) rows_chunk = 256;
    if (rows_chunk > ROWS_TOTAL) rows_chunk = ROWS_TOTAL;

    for (long r0 = 0; r0 < ROWS_TOTAL; r0 += rows_chunk) {
        long rows = ROWS_TOTAL - r0;
        if (rows > rows_chunk) rows = rows_chunk;
        long nbc = rows >> 8;                  // whole b's this chunk
        int  mt  = (int)(rows >> 8);           // 256-row m-tiles

        // Stage A: S = X2b @ Wb^T.  M = rows, N = 32768, K = 512.
        dim3 gA((unsigned)((32768 / BN) * mt), 1, 1);
        gemm_nt_r6<__bf16><<<gA, 512, 0, stream>>>(
            x2b + r0 * KDIM, Wb, S, nullptr, 32768, mt, 0, 0, 0);

        // Stage B: z-batched over this chunk's b's -> fp32 out (+bias).
        dim3 gB2(16384 / BN, 1, (unsigned)nbc);
        gemm_nt_r6<float><<<gB2, 512, 0, stream>>>(
            x1b + r0 * KDIM,                   // X1_b rows
            S,                                 // S_b as [16384 x 512]
            out + r0 * 16384,                  // out_b as [256 x 16384]
            bs, 16384, 1,
            256L * KDIM, 256L * ROW_ELEMS, 256L * 16384);
    }
}